// Round 8
// baseline (29220.493 us; speedup 1.0000x reference)
//
#include <hip/hip_runtime.h>

// ---------------------------------------------------------------------------
// LSTM T=2048, B=256, IN=64, H=256 (gates 4H=1024)
// R8: 8 teams x 2 WGs (column halves) = 16 WGs x 512 threads. Weights fully
// register-resident (160 regs/wave in unified VGPR/AGPR file). NEW: each team
// multiplexes TWO sample groups (A,B), alternating phases A(t),B(t). Group
// g's peer flag is checked and its 8KB slice load ISSUED one full phase
// before consumption -> LLC RT and flag propagation hide under the other
// group's compute; desync self-corrects (removes R7's 42ms bad equilibrium).
// Per-group exchange protocol is byte-identical to R6 (HW-verified): publish
// [row][col] hi/lo sc1 stores -> vmcnt(0) -> per-wave relaxed atomicAdd on
// padded flag; consumer gates loads on flag in program order. No fences.
// Numerics identical to R1..R7: bf16 weights, hi/lo bf16 A, fp32 acc.
// ---------------------------------------------------------------------------

#define T_SEQ 2048
#define B_SZ  256
#define IN_SZ 64
#define H_SZ  256
#define G4    1024
#define NKF   10
#define NCT   64
#define FRAG_BYTES (NCT * NKF * 64 * 16)      // 655360 B
#define BIAS_OFF   FRAG_BYTES
#define FLAGS_OFF  (FRAG_BYTES + 8192)        // 16wg x 2grp flags, 128B apart
#define XBUF_OFF   (FRAG_BYTES + 16384)       // 16wg x 2grp x 2slot x 8KB = 512KB
// LDS map
#define ROW_B    768
#define BUF_B    (16 * ROW_B)                 // 12288; 4 bufs (2 grp x 2 par)
#define PEER_OFF (4 * BUF_B)                  // 49152; 16 rows x 544B
#define PROW     544
#define PSW_OFF  (PEER_OFF + 8704)            // 57856; 8 waves x 1088B
#define LDS_BYTES (PSW_OFF + 8704)            // 66560

typedef float f32x4 __attribute__((ext_vector_type(4)));
typedef short s16x8 __attribute__((ext_vector_type(8)));
typedef short s16x2 __attribute__((ext_vector_type(2)));
typedef unsigned long long u64;
typedef u64 u64x2 __attribute__((ext_vector_type(2)));

__device__ __forceinline__ short f2bf(float f) {          // RNE f32->bf16
    unsigned u = __builtin_bit_cast(unsigned, f);
    u = u + 0x7fffu + ((u >> 16) & 1u);
    return (short)(u >> 16);
}
__device__ __forceinline__ float bf2f(short s) {
    return __builtin_bit_cast(float, ((unsigned)(unsigned short)s) << 16);
}
__device__ __forceinline__ float fsigmoid(float v) {
    return __builtin_amdgcn_rcpf(1.0f + __expf(-v));
}
__device__ __forceinline__ float ftanh(float v) {
    return 2.0f * __builtin_amdgcn_rcpf(1.0f + __expf(-2.0f * v)) - 1.0f;
}
// A-matrix row: [0,128)B x_hi | [128,384)B own-h hi | +384 same lo; XOR-swz.
__device__ __forceinline__ short* aptr(char* base, int row, int off) {
    return (short*)(base + row * ROW_B + (off ^ ((row & 7) << 4)));
}

// --- repack Wx|Wh into bf16 MFMA B-fragments -------------------------------
// fragment (ct,kf), lane l, elem j <-> k = kf*32 + (l>>4)*8 + j, n = ct*16+(l&15)
__global__ void repack_kernel(const float* __restrict__ Wx,
                              const float* __restrict__ Wh,
                              const float* __restrict__ bx,
                              const float* __restrict__ bh,
                              s16x8* __restrict__ fragbuf,
                              float* __restrict__ bias) {
    const int blk  = blockIdx.x;
    const int lane = threadIdx.x;
    const int ct = blk / NKF;
    const int kf = blk - ct * NKF;
    const int n  = ct * 16 + (lane & 15);
    const int q  = lane >> 4;
    s16x8 frag;
#pragma unroll
    for (int j = 0; j < 8; ++j) {
        const int k = kf * 32 + q * 8 + j;
        const float v = (k < IN_SZ) ? Wx[k * G4 + n] : Wh[(k - IN_SZ) * G4 + n];
        frag[j] = f2bf(v);
    }
    fragbuf[blk * 64 + lane] = frag;
    if (blk < 16) {
        const int i = blk * 64 + lane;
        bias[i] = bx[i] + bh[i];
    }
}

__global__ void init_flags(unsigned* __restrict__ flags) {
    for (int i = threadIdx.x; i < 1024; i += 256) flags[i] = 0u;
}

// One LSTM step for one sample group. All indices static; state via refs.
#define PHASE(CS, XV0, XV1, PV0, PV1, RDY, GIDX, SBASE, XP, ORDY, OPV0, OPV1, OGIDX, ONT) \
do {                                                                           \
    const int cur = t & 1;                                                     \
    char* bufC = lds + ((GIDX) * 2 + cur) * BUF_B;                             \
    char* bufN = lds + ((GIDX) * 2 + (cur ^ 1)) * BUF_B;                       \
    char* mySlot = xbuf + ((size_t)((bid  * 2 + (GIDX)) * 2 + cur)) * 8192;    \
    const unsigned tgt = 8u * (unsigned)t;                                     \
    const bool fast = (t > 0) && __all((int)((RDY) >= tgt));                   \
    f32x4 acc[4], acl[4];                                                      \
    _Pragma("unroll") for (int ci = 0; ci < 4; ++ci) {                         \
        acc[ci] = (f32x4){bs[ci], bs[ci], bs[ci], bs[ci]};                     \
        acl[ci] = (f32x4){0.f, 0.f, 0.f, 0.f};                                 \
    }                                                                          \
    _Pragma("unroll") for (int j = 0; j < 6; ++j) {                            \
        const s16x8 ah = *(const s16x8*)aptr(bufC, ln, j * 64 + q * 16);       \
        const s16x8 al = *(const s16x8*)aptr(bufC, ln, 384 + j * 64 + q * 16); \
        _Pragma("unroll") for (int ci = 0; ci < 4; ++ci) {                     \
            acc[ci] = __builtin_amdgcn_mfma_f32_16x16x32_bf16(ah, wt[ci][j], acc[ci], 0, 0, 0); \
            acl[ci] = __builtin_amdgcn_mfma_f32_16x16x32_bf16(al, wt[ci][j], acl[ci], 0, 0, 0); \
        }                                                                      \
    }                                                                          \
    if (t > 0) {                                                               \
        if (!fast) { /* rare after warmup: spin then load */                   \
            char* pSlot = xbuf + ((size_t)((peer * 2 + (GIDX)) * 2 + ((t - 1) & 1))) * 8192; \
            while (__hip_atomic_load(&flags[(peer * 2 + (GIDX)) * 32],         \
                   __ATOMIC_RELAXED, __HIP_MEMORY_SCOPE_AGENT) < tgt)          \
                __builtin_amdgcn_s_sleep(1);                                   \
            asm volatile("" ::: "memory");                                     \
            const u64* psrc = (const u64*)(pSlot + sh * 4096 + sm * 256 + sc * 16); \
            PV0 = __hip_atomic_load(psrc,     __ATOMIC_RELAXED, __HIP_MEMORY_SCOPE_AGENT); \
            PV1 = __hip_atomic_load(psrc + 1, __ATOMIC_RELAXED, __HIP_MEMORY_SCOPE_AGENT); \
        }                                                                      \
        *(u64x2*)(peerL + sm * PROW + sh * 272 + sc * 16) = (u64x2){PV0, PV1}; \
        __syncthreads();                                                       \
        _Pragma("unroll") for (int jj = 0; jj < 4; ++jj) {                     \
            const s16x8 ah = *(const s16x8*)(peerL + ln * PROW + jj * 64 + q * 16); \
            const s16x8 al = *(const s16x8*)(peerL + ln * PROW + 272 + jj * 64 + q * 16); \
            _Pragma("unroll") for (int ci = 0; ci < 4; ++ci) {                 \
                acc[ci] = __builtin_amdgcn_mfma_f32_16x16x32_bf16(ah, wt[ci][6 + jj], acc[ci], 0, 0, 0); \
                acl[ci] = __builtin_amdgcn_mfma_f32_16x16x32_bf16(al, wt[ci][6 + jj], acl[ci], 0, 0, 0); \
            }                                                                  \
        }                                                                      \
    }                                                                          \
    _Pragma("unroll") for (int ci = 0; ci < 4; ++ci) acc[ci] += acl[ci];       \
    const bool last = (t == T_SEQ - 1);                                        \
    float hvr[4]; float cfr[4]; unsigned pu[4];                                \
    _Pragma("unroll") for (int r = 0; r < 4; ++r) {                            \
        const float fv = fsigmoid(acc[0][r]);                                  \
        const float iv = fsigmoid(acc[1][r]);                                  \
        const float ov = fsigmoid(acc[2][r]);                                  \
        const float gv = ftanh(acc[3][r]);                                     \
        const float cf = fv * (CS)[r] + iv * gv;                               \
        (CS)[r] = cf; cfr[r] = cf;                                             \
        const float hv = ov * ftanh(cf);                                       \
        hvr[r] = hv;                                                           \
        const short hh = f2bf(hv);                                             \
        const short hl = f2bf(hv - bf2f(hh));                                  \
        pu[r] = ((unsigned)(unsigned short)hh) | (((unsigned)(unsigned short)hl) << 16); \
    }                                                                          \
    _Pragma("unroll") for (int r = 0; r < 4; ++r) psw[ln * 17 + q * 4 + r] = pu[r]; \
    {   /* wave-private transpose -> publish [row][col] hi/lo */               \
        const int m2 = lane & 15;                                              \
        const int cc = lane >> 4;                                              \
        const unsigned t0 = psw[(cc * 4 + 0) * 17 + m2];                       \
        const unsigned t1 = psw[(cc * 4 + 1) * 17 + m2];                       \
        const unsigned t2 = psw[(cc * 4 + 2) * 17 + m2];                       \
        const unsigned t3 = psw[(cc * 4 + 3) * 17 + m2];                       \
        const u64 hi64 = (u64)(t0 & 0xffffu) | ((u64)(t1 & 0xffffu) << 16)     \
                       | ((u64)(t2 & 0xffffu) << 32) | ((u64)(t3 & 0xffffu) << 48); \
        const u64 lo64 = (u64)(t0 >> 16) | ((u64)(t1 >> 16) << 16)             \
                       | ((u64)(t2 >> 16) << 32) | ((u64)(t3 >> 16) << 48);    \
        const int off = m2 * 256 + w * 32 + cc * 8;                            \
        __hip_atomic_store((u64*)(mySlot + off),        hi64, __ATOMIC_RELAXED, __HIP_MEMORY_SCOPE_AGENT); \
        __hip_atomic_store((u64*)(mySlot + 4096 + off), lo64, __ATOMIC_RELAXED, __HIP_MEMORY_SCOPE_AGENT); \
    }                                                                          \
    asm volatile("s_waitcnt vmcnt(0)" ::: "memory");                           \
    if (lane == 0)                                                             \
        (void)__hip_atomic_fetch_add(&flags[(bid * 2 + (GIDX)) * 32], 1u,      \
                                     __ATOMIC_RELAXED, __HIP_MEMORY_SCOPE_AGENT); \
    float* hs = out + (size_t)t * (B_SZ * H_SZ) + (size_t)(SBASE) * H_SZ;      \
    _Pragma("unroll") for (int r = 0; r < 4; ++r) {                            \
        const int m = q * 4 + r;                                               \
        __builtin_nontemporal_store(hvr[r], hs + m * H_SZ + col);              \
        *aptr(bufN, m, 128 + colp * 2) = (short)(pu[r] & 0xffffu);             \
        *aptr(bufN, m, 512 + colp * 2) = (short)(pu[r] >> 16);                 \
        if (last) {                                                            \
            float* fin = out + (size_t)T_SEQ * B_SZ * H_SZ;                    \
            fin[((SBASE) + m) * H_SZ + col] = hvr[r];                          \
            fin[B_SZ * H_SZ + ((SBASE) + m) * H_SZ + col] = cfr[r];            \
        }                                                                      \
    }                                                                          \
    {   /* stage x_{t+1} (in regs) into bufN, prefetch x_{t+2} */              \
        const short h0 = f2bf(XV0), h1 = f2bf(XV1);                            \
        const short l0 = f2bf((XV0) - bf2f(h0));                               \
        const short l1 = f2bf((XV1) - bf2f(h1));                               \
        *(s16x2*)aptr(bufN, xrow, xi * 2)       = (s16x2){h0, h1};             \
        *(s16x2*)aptr(bufN, xrow, 384 + xi * 2) = (s16x2){l0, l1};             \
        const int tn = (t + 2 < T_SEQ) ? t + 2 : T_SEQ - 1;                    \
        const float* xp2 = (XP) + (size_t)tn * (B_SZ * IN_SZ);                 \
        XV0 = xp2[0]; XV1 = xp2[1];                                            \
    }                                                                          \
    /* prep OTHER group's step ONT: flag-gated spec load, lands next phase */  \
    if ((ONT) > 0 && (ONT) < T_SEQ) {                                          \
        ORDY = __hip_atomic_load(&flags[(peer * 2 + (OGIDX)) * 32],            \
                                 __ATOMIC_RELAXED, __HIP_MEMORY_SCOPE_AGENT);  \
        if (__all((int)((ORDY) >= 8u * (unsigned)(ONT)))) {                    \
            const u64* ps2 = (const u64*)(xbuf                                 \
                + ((size_t)((peer * 2 + (OGIDX)) * 2 + (((ONT) - 1) & 1))) * 8192 \
                + sh * 4096 + sm * 256 + sc * 16);                             \
            OPV0 = __hip_atomic_load(ps2,     __ATOMIC_RELAXED, __HIP_MEMORY_SCOPE_AGENT); \
            OPV1 = __hip_atomic_load(ps2 + 1, __ATOMIC_RELAXED, __HIP_MEMORY_SCOPE_AGENT); \
        }                                                                      \
    }                                                                          \
    __syncthreads();                                                           \
} while (0)

__global__ __launch_bounds__(512, 2) void lstm_persist(
        const float* __restrict__ x,
        const s16x8* __restrict__ fragbuf,
        const float* __restrict__ bias,
        float* __restrict__ out,
        unsigned* __restrict__ flags,
        char* __restrict__ xbuf) {
    __shared__ char lds[LDS_BYTES];

    const int tid  = threadIdx.x;
    const int lane = tid & 63;
    const int w    = tid >> 6;
    const int q    = lane >> 4;
    const int ln   = lane & 15;
    const int bid  = blockIdx.x;          // 0..15
    const int team = bid >> 1;            // 0..7
    const int p    = bid & 1;             // column half
    const int peer = bid ^ 1;
    const int S_A  = team * 32;           // group A sample base
    const int S_B  = team * 32 + 16;      // group B sample base
    const int hb   = p * 8 + w;
    const int col  = hb * 16 + ln;        // global hidden col (both groups)
    const int colp = w * 16 + ln;         // col within own half

    for (int i = tid; i < LDS_BYTES / 4; i += 512) ((int*)lds)[i] = 0;

    // weights: wt[ci][j], j order: 0,1=x; 2..5=own h; 6..9=peer h
    s16x8 wt[4][10];
#pragma unroll
    for (int ci = 0; ci < 4; ++ci) {
        const int ct = ci * 16 + hb;
#pragma unroll
        for (int j = 0; j < 10; ++j) {
            const int kf = (j < 2) ? j
                         : (j < 6 ? 2 + 4 * p + (j - 2)
                                  : 2 + 4 * (1 - p) + (j - 6));
            wt[ci][j] = fragbuf[(size_t)(ct * NKF + kf) * 64 + lane];
        }
    }
    float bs[4];
#pragma unroll
    for (int ci = 0; ci < 4; ++ci) bs[ci] = bias[(ci * 16 + hb) * 16 + ln];

    f32x4 csA = {0.f, 0.f, 0.f, 0.f};
    f32x4 csB = {0.f, 0.f, 0.f, 0.f};

    const int xrow = tid >> 5;            // 0..15
    const int xi   = (tid & 31) << 1;     // 0..62
    const float* xpA = x + (size_t)(S_A + xrow) * IN_SZ + xi;
    const float* xpB = x + (size_t)(S_B + xrow) * IN_SZ + xi;
    float xA0 = xpA[0], xA1 = xpA[1];     // x_0 group A
    float xB0 = xpB[0], xB1 = xpB[1];     // x_0 group B

    // stage x_0 into buf(A,0) and buf(B,0)
    {
        const short h0 = f2bf(xA0), h1 = f2bf(xA1);
        const short l0 = f2bf(xA0 - bf2f(h0));
        const short l1 = f2bf(xA1 - bf2f(h1));
        *(s16x2*)aptr(lds, xrow, xi * 2)       = (s16x2){h0, h1};
        *(s16x2*)aptr(lds, xrow, 384 + xi * 2) = (s16x2){l0, l1};
    }
    {
        const short h0 = f2bf(xB0), h1 = f2bf(xB1);
        const short l0 = f2bf(xB0 - bf2f(h0));
        const short l1 = f2bf(xB1 - bf2f(h1));
        char* bB0 = lds + 2 * BUF_B;
        *(s16x2*)aptr(bB0, xrow, xi * 2)       = (s16x2){h0, h1};
        *(s16x2*)aptr(bB0, xrow, 384 + xi * 2) = (s16x2){l0, l1};
    }
    {   // prefetch x_1 for both groups
        const float* a = xpA + (size_t)(B_SZ * IN_SZ);
        const float* b = xpB + (size_t)(B_SZ * IN_SZ);
        xA0 = a[0]; xA1 = a[1]; xB0 = b[0]; xB1 = b[1];
    }

    char* peerL = lds + PEER_OFF;
    unsigned* psw = (unsigned*)(lds + PSW_OFF) + w * 272;   // wave-private 16x17
    const int sh = tid >> 8;              // consumer staging: 0:hi 1:lo
    const int sm = (tid >> 4) & 15;       // row
    const int sc = tid & 15;              // 16B chunk
    u64 pvA0 = 0, pvA1 = 0, pvB0 = 0, pvB1 = 0;
    unsigned rdyA = 0, rdyB = 0;

    __syncthreads();

    for (int t = 0; t < T_SEQ; ++t) {
        // phase A(t): preps group B for step t
        PHASE(csA, xA0, xA1, pvA0, pvA1, rdyA, 0, S_A, xpA,
              rdyB, pvB0, pvB1, 1, t);
        // phase B(t): preps group A for step t+1
        PHASE(csB, xB0, xB1, pvB0, pvB1, rdyB, 1, S_B, xpB,
              rdyA, pvA0, pvA1, 0, t + 1);
    }
}

extern "C" void kernel_launch(void* const* d_in, const int* in_sizes, int n_in,
                              void* d_out, int out_size, void* d_ws, size_t ws_size,
                              hipStream_t stream) {
    const float* x  = (const float*)d_in[0];
    const float* Wx = (const float*)d_in[1];
    const float* Wh = (const float*)d_in[2];
    const float* bx = (const float*)d_in[3];
    const float* bh = (const float*)d_in[4];
    float* out = (float*)d_out;

    s16x8*    fragbuf = (s16x8*)d_ws;
    float*    bias    = (float*)((char*)d_ws + BIAS_OFF);
    unsigned* flags   = (unsigned*)((char*)d_ws + FLAGS_OFF);
    char*     xbuf    = (char*)d_ws + XBUF_OFF;

    repack_kernel<<<NCT * NKF, 64, 0, stream>>>(Wx, Wh, bx, bh, fragbuf, bias);
    init_flags<<<1, 256, 0, stream>>>(flags);
    lstm_persist<<<16, 512, 0, stream>>>(x, fragbuf, bias, out, flags, xbuf);
}